// Round 1
// baseline (1439.864 us; speedup 1.0000x reference)
//
#include <hip/hip_runtime.h>
#include <hip/hip_bf16.h>

// Problem constants
static constexpr int PN = 16384;  // paths
static constexpr int TT = 8;      // seq len
static constexpr int LN = 4096;   // links
static constexpr int KG = 16;     // path_to_link K
static constexpr int NN = 2048;   // nodes
static constexpr int K2G = 32;    // path_to_node K2
static constexpr int MG = 8;      // link_to_node M
static constexpr int DD = 64;     // state dim
static constexpr int ITER = 8;

__device__ __forceinline__ float sigmoidf_(float x) {
    return 1.0f / (1.0f + __expf(-x));
}
__device__ __forceinline__ float tanhf_(float x) {
    // tanh(x) = 1 - 2/(exp(2x)+1); saturates correctly for large |x|
    float e = __expf(2.0f * x);
    return 1.0f - 2.0f / (e + 1.0f);
}
__device__ __forceinline__ float softplusf_(float x) {
    // stable: max(x,0) + log1p(exp(-|x|))
    return fmaxf(x, 0.0f) + log1pf(__expf(-fabsf(x)));
}
__device__ __forceinline__ unsigned short f2bf(float f) {
    unsigned int x = __float_as_uint(f);
    unsigned int r = (x + 0x7fffu + ((x >> 16) & 1u)) >> 16;
    return (unsigned short)r;
}
__device__ __forceinline__ float bf2f(unsigned short u) {
    return __uint_as_float(((unsigned int)u) << 16);
}

// ---------------------------------------------------------------------------
// K1: path encoder MLP2 (3 -> 64 -> 64), 4 rows/block, thread d per row
// ---------------------------------------------------------------------------
__global__ __launch_bounds__(256) void k_path_encode(
    const float* __restrict__ ft, const float* __restrict__ fpk,
    const float* __restrict__ fps,
    const float* __restrict__ w1, const float* __restrict__ b1,
    const float* __restrict__ w2, const float* __restrict__ b2,
    float* __restrict__ path_state)
{
    __shared__ float h1s[4][64];
    int tid = threadIdx.x;
    int rl = tid >> 6, d = tid & 63;
    int row = blockIdx.x * 4 + rl;
    float x0 = ft[row]  * 1e-4f;
    float x1 = fpk[row] * 1e-3f;
    float x2 = fps[row] * 1e-3f;
    float h = b1[d] + x0 * w1[d] + x1 * w1[64 + d] + x2 * w1[128 + d];
    h1s[rl][d] = fmaxf(h, 0.0f);
    __syncthreads();
    float acc = b2[d];
#pragma unroll 8
    for (int k = 0; k < 64; ++k) acc += h1s[rl][k] * w2[k * 64 + d];
    path_state[(size_t)row * 64 + d] = fmaxf(acc, 0.0f);
}

// ---------------------------------------------------------------------------
// K2: link encoder (load gather + MLP2 3 -> 64 -> 64)
// ---------------------------------------------------------------------------
__global__ __launch_bounds__(256) void k_link_encode(
    const float* __restrict__ cap, const float* __restrict__ ft,
    const int* __restrict__ ptl, const int* __restrict__ ldt,
    const float* __restrict__ w1, const float* __restrict__ b1,
    const float* __restrict__ w2, const float* __restrict__ b2,
    float* __restrict__ link_state)
{
    __shared__ float h1s[4][64];
    int tid = threadIdx.x;
    int rl = tid >> 6, d = tid & 63;
    int row = blockIdx.x * 4 + rl;
    float v = 0.0f;
    if (d < 16) v = ft[ptl[(row * 16 + d) * 2]];
    // reduce lanes 0..15 into lane 0 of the wave
    v += __shfl_down(v, 8);
    v += __shfl_down(v, 4);
    v += __shfl_down(v, 2);
    v += __shfl_down(v, 1);
    float ssum = __shfl(v, 0);
    float c = cap[row];
    float load = ssum / (c * 1e9f);
    float x0 = c * 0.01f;
    float x1 = load;
    float x2 = (ldt[row] == 0) ? 1.0f : 0.0f;
    float h = b1[d] + x0 * w1[d] + x1 * w1[64 + d] + x2 * w1[128 + d];
    h1s[rl][d] = fmaxf(h, 0.0f);
    __syncthreads();
    float acc = b2[d];
#pragma unroll 8
    for (int k = 0; k < 64; ++k) acc += h1s[rl][k] * w2[k * 64 + d];
    link_state[(size_t)row * 64 + d] = fmaxf(acc, 0.0f);
}

// ---------------------------------------------------------------------------
// K3: device encoder (link mean gather + MLP2 2 -> 64 -> 64)
// ---------------------------------------------------------------------------
__global__ __launch_bounds__(256) void k_device_encode(
    const float* __restrict__ link_state, const int* __restrict__ ltn,
    const int* __restrict__ nodes,
    const float* __restrict__ w1, const float* __restrict__ b1,
    const float* __restrict__ w2, const float* __restrict__ b2,
    float* __restrict__ device_state)
{
    __shared__ float h1s[4][64];
    int tid = threadIdx.x;
    int rl = tid >> 6, d = tid & 63;
    int row = blockIdx.x * 4 + rl;
    float s = 0.0f;
#pragma unroll
    for (int m = 0; m < MG; ++m)
        s += link_state[(size_t)ltn[row * MG + m] * 64 + d];
    // sum across all 64 lanes (features)
#pragma unroll
    for (int o = 32; o > 0; o >>= 1) s += __shfl_xor(s, o);
    float dlm = s * (1.0f / 64.0f);
    float enc = (nodes[row] == 0) ? 1.0f : 0.0f;
    float h = b1[d] + enc * w1[d] + dlm * w1[64 + d];
    h1s[rl][d] = fmaxf(h, 0.0f);
    __syncthreads();
    float acc = b2[d];
#pragma unroll 8
    for (int k = 0; k < 64; ++k) acc += h1s[rl][k] * w2[k * 64 + d];
    device_state[(size_t)row * 64 + d] = fmaxf(acc, 0.0f);
}

// ---------------------------------------------------------------------------
// K4: xproj = (link_state[ltp] + device_state[ntp]) @ pgru_wx + bx  -> bf16
// 64 rows/block, wx staged in LDS (48KB), thread = 4 rows x 12 cols
// ---------------------------------------------------------------------------
__global__ __launch_bounds__(256) void k_xproj(
    const float* __restrict__ ls, const float* __restrict__ dst,
    const int* __restrict__ ltp, const int* __restrict__ ntp,
    const float* __restrict__ wx, const float* __restrict__ bx,
    unsigned short* __restrict__ xproj)
{
    __shared__ __align__(16) float Ws[64 * 192];
    __shared__ __align__(16) float Xs[64][68];
    __shared__ float bxs[192];
    int tid = threadIdx.x;
    int base = blockIdx.x * 64;
    // stage W (12288 floats = 3072 float4)
    {
        const float4* w4 = (const float4*)wx;
        float4* s4 = (float4*)Ws;
#pragma unroll
        for (int i = 0; i < 12; ++i) s4[i * 256 + tid] = w4[i * 256 + tid];
        if (tid < 192) bxs[tid] = bx[tid];
    }
    // stage X rows (gather + add)
    {
        int rl = tid >> 2, q = tid & 3;
        int grow = base + rl;
        int il = ltp[grow], in = ntp[grow];
        const float4* l4 = (const float4*)(ls + (size_t)il * 64);
        const float4* n4 = (const float4*)(dst + (size_t)in * 64);
#pragma unroll
        for (int j = 0; j < 4; ++j) {
            float4 a = l4[q * 4 + j], b = n4[q * 4 + j];
            float4 r;
            r.x = a.x + b.x; r.y = a.y + b.y; r.z = a.z + b.z; r.w = a.w + b.w;
            *(float4*)&Xs[rl][q * 16 + j * 4] = r;
        }
    }
    __syncthreads();
    int rg = tid >> 4, cg = tid & 15;  // rows rg*4.., cols cg*12..
    float acc[4][12];
#pragma unroll
    for (int r = 0; r < 4; ++r)
#pragma unroll
        for (int j = 0; j < 12; ++j) acc[r][j] = 0.0f;
#pragma unroll 8
    for (int kk = 0; kk < 64; ++kk) {
        float4 w0 = *(const float4*)&Ws[kk * 192 + cg * 12];
        float4 w1v = *(const float4*)&Ws[kk * 192 + cg * 12 + 4];
        float4 w2v = *(const float4*)&Ws[kk * 192 + cg * 12 + 8];
        float wv[12] = {w0.x, w0.y, w0.z, w0.w, w1v.x, w1v.y, w1v.z, w1v.w,
                        w2v.x, w2v.y, w2v.z, w2v.w};
#pragma unroll
        for (int r = 0; r < 4; ++r) {
            float xv = Xs[rg * 4 + r][kk];
#pragma unroll
            for (int j = 0; j < 12; ++j) acc[r][j] += xv * wv[j];
        }
    }
#pragma unroll
    for (int r = 0; r < 4; ++r) {
        int grow = base + rg * 4 + r;
        ushort4 hb[3];
        unsigned short* hu = (unsigned short*)hb;
#pragma unroll
        for (int j = 0; j < 12; ++j)
            hu[j] = f2bf(acc[r][j] + bxs[cg * 12 + j]);
        ushort4* dstp = (ushort4*)(xproj + (size_t)grow * 192 + cg * 12);
        dstp[0] = hb[0]; dstp[1] = hb[1]; dstp[2] = hb[2];
    }
}

// ---------------------------------------------------------------------------
// K5: path GRU scan, 8 steps fused (no cross-path dependency).
// 32 paths/block; pgru_wh in LDS; thread owns 2 rows x (4 cols x 3 gates).
// Writes pss[:, 1..8] and final path_state.
// ---------------------------------------------------------------------------
__global__ __launch_bounds__(256) void k_pscan(
    const float* __restrict__ wh, const float* __restrict__ bh,
    const unsigned short* __restrict__ xproj,
    float* __restrict__ path_state, float* __restrict__ pss)
{
    __shared__ __align__(16) float Ws[64 * 192];
    __shared__ __align__(16) float Hs[32][68];
    __shared__ float bhs[192];
    int tid = threadIdx.x;
    int p0 = blockIdx.x * 32;
    {
        const float4* w4 = (const float4*)wh;
        float4* s4 = (float4*)Ws;
#pragma unroll
        for (int i = 0; i < 12; ++i) s4[i * 256 + tid] = w4[i * 256 + tid];
        if (tid < 192) bhs[tid] = bh[tid];
    }
    for (int i = tid; i < 512; i += 256) {
        int r = i >> 4, q = i & 15;
        *(float4*)&Hs[r][q * 4] =
            *(const float4*)&path_state[(size_t)(p0 + r) * 64 + q * 4];
    }
    __syncthreads();

    int rg = tid >> 4, cg = tid & 15;  // rows rg*2+r, col base d0=cg*4
    int d0 = cg * 4;
    for (int t = 0; t < TT; ++t) {
        float az[2][4], ar_[2][4], ac[2][4];
#pragma unroll
        for (int r = 0; r < 2; ++r)
#pragma unroll
            for (int j = 0; j < 4; ++j) { az[r][j] = 0.f; ar_[r][j] = 0.f; ac[r][j] = 0.f; }
#pragma unroll 8
        for (int kk = 0; kk < 64; ++kk) {
            float4 wz = *(const float4*)&Ws[kk * 192 + d0];
            float4 wr = *(const float4*)&Ws[kk * 192 + 64 + d0];
            float4 wc = *(const float4*)&Ws[kk * 192 + 128 + d0];
#pragma unroll
            for (int r = 0; r < 2; ++r) {
                float xv = Hs[rg * 2 + r][kk];
                az[r][0] += xv * wz.x; az[r][1] += xv * wz.y;
                az[r][2] += xv * wz.z; az[r][3] += xv * wz.w;
                ar_[r][0] += xv * wr.x; ar_[r][1] += xv * wr.y;
                ar_[r][2] += xv * wr.z; ar_[r][3] += xv * wr.w;
                ac[r][0] += xv * wc.x; ac[r][1] += xv * wc.y;
                ac[r][2] += xv * wc.z; ac[r][3] += xv * wc.w;
            }
        }
        float hn[2][4];
#pragma unroll
        for (int r = 0; r < 2; ++r) {
            int p = p0 + rg * 2 + r;
            const unsigned short* xp = xproj + (size_t)(p * 8 + t) * 192 + d0;
            ushort4 uz = *(const ushort4*)(xp);
            ushort4 ur = *(const ushort4*)(xp + 64);
            ushort4 uc = *(const ushort4*)(xp + 128);
            unsigned short uza[4] = {uz.x, uz.y, uz.z, uz.w};
            unsigned short ura[4] = {ur.x, ur.y, ur.z, ur.w};
            unsigned short uca[4] = {uc.x, uc.y, uc.z, uc.w};
#pragma unroll
            for (int j = 0; j < 4; ++j) {
                int d = d0 + j;
                float hz = az[r][j] + bhs[d];
                float hr = ar_[r][j] + bhs[64 + d];
                float hc = ac[r][j] + bhs[128 + d];
                float zz = sigmoidf_(bf2f(uza[j]) + hz);
                float rr = sigmoidf_(bf2f(ura[j]) + hr);
                float cc = tanhf_(bf2f(uca[j]) + rr * hc);
                float hold = Hs[rg * 2 + r][d];
                hn[r][j] = zz * hold + (1.0f - zz) * cc;
            }
            float4 st;
            st.x = hn[r][0]; st.y = hn[r][1]; st.z = hn[r][2]; st.w = hn[r][3];
            *(float4*)&pss[((size_t)p * 9 + t + 1) * 64 + d0] = st;
        }
        __syncthreads();
#pragma unroll
        for (int r = 0; r < 2; ++r) {
            Hs[rg * 2 + r][d0]     = hn[r][0];
            Hs[rg * 2 + r][d0 + 1] = hn[r][1];
            Hs[rg * 2 + r][d0 + 2] = hn[r][2];
            Hs[rg * 2 + r][d0 + 3] = hn[r][3];
        }
        __syncthreads();
    }
    for (int i = tid; i < 512; i += 256) {
        int r = i >> 4, q = i & 15;
        *(float4*)&path_state[(size_t)(p0 + r) * 64 + q * 4] =
            *(const float4*)&Hs[r][q * 4];
    }
}

// ---------------------------------------------------------------------------
// K6/K7: link/device GRU update. 8 rows/block. agg = sum_k pss[idx,tidx];
// dual GEMM (agg@wx, h@wh) with W streamed from global (L2-cached); gates.
// ---------------------------------------------------------------------------
__global__ __launch_bounds__(256) void k_edge_update(
    const float* __restrict__ wx, const float* __restrict__ wh,
    const float* __restrict__ bx, const float* __restrict__ bh,
    const int* __restrict__ p2e, int Kg,
    const float* __restrict__ pss, float* __restrict__ state)
{
    __shared__ __align__(16) float Ag[8][68];
    __shared__ __align__(16) float Hb[8][68];
    int tid = threadIdx.x;
    int r0 = blockIdx.x * 8;
    {
        int rl = tid >> 5, q = tid & 31;
        int row = r0 + rl;
        float2 s; s.x = 0.f; s.y = 0.f;
        for (int k = 0; k < Kg; ++k) {
            int pi = p2e[((size_t)row * Kg + k) * 2];
            int ti = p2e[((size_t)row * Kg + k) * 2 + 1];
            const float2* src = (const float2*)(pss + ((size_t)pi * 9 + ti) * 64);
            float2 v = src[q];
            s.x += v.x; s.y += v.y;
        }
        *(float2*)&Ag[rl][q * 2] = s;
        *(float2*)&Hb[rl][q * 2] = *(const float2*)(state + (size_t)row * 64 + q * 2);
    }
    __syncthreads();
    int rg = tid >> 5, cg = tid & 31;
    int row = r0 + rg;
    int d0 = cg * 2;
    float ax[6], ah[6];
#pragma unroll
    for (int i = 0; i < 6; ++i) { ax[i] = 0.f; ah[i] = 0.f; }
#pragma unroll 4
    for (int kk = 0; kk < 64; ++kk) {
        float xa = Ag[rg][kk], xh = Hb[rg][kk];
#pragma unroll
        for (int g = 0; g < 3; ++g) {
            float2 wxv = *(const float2*)(wx + kk * 192 + g * 64 + d0);
            float2 whv = *(const float2*)(wh + kk * 192 + g * 64 + d0);
            ax[g * 2]     += xa * wxv.x;
            ax[g * 2 + 1] += xa * wxv.y;
            ah[g * 2]     += xh * whv.x;
            ah[g * 2 + 1] += xh * whv.y;
        }
    }
    float2 hnew;
    float* hnp = (float*)&hnew;
#pragma unroll
    for (int j = 0; j < 2; ++j) {
        int d = d0 + j;
        float xz = ax[j] + bx[d];
        float xr = ax[2 + j] + bx[64 + d];
        float xc = ax[4 + j] + bx[128 + d];
        float hz = ah[j] + bh[d];
        float hr = ah[2 + j] + bh[64 + d];
        float hc = ah[4 + j] + bh[128 + d];
        float z = sigmoidf_(xz + hz);
        float r = sigmoidf_(xr + hr);
        float c = tanhf_(xc + r * hc);
        float hold = Hb[rg][d];
        hnp[j] = z * hold + (1.0f - z) * c;
    }
    *(float2*)&state[(size_t)row * 64 + d0] = hnew;
}

// ---------------------------------------------------------------------------
// K8: readout MLP (64->32->16->1), softplus, delay sum. One path per block.
// ---------------------------------------------------------------------------
__global__ __launch_bounds__(256) void k_readout(
    const float* __restrict__ pss,
    const float* __restrict__ w1, const float* __restrict__ b1,
    const float* __restrict__ w2, const float* __restrict__ b2,
    const float* __restrict__ w3, const float* __restrict__ b3,
    const float* __restrict__ cap, const int* __restrict__ ltp,
    float* __restrict__ out)
{
    __shared__ __align__(16) float Pr[8][68];
    __shared__ float H1[8][33];
    __shared__ float H2[8][17];
    __shared__ float OC[8];
    int tid = threadIdx.x;
    int p = blockIdx.x;
    if (tid < 128) {
        int r = tid >> 4, q = tid & 15;
        *(float4*)&Pr[r][q * 4] =
            *(const float4*)&pss[((size_t)p * 9 + r + 1) * 64 + q * 4];
    }
    __syncthreads();
    {
        int t = tid >> 5, c = tid & 31;
        float acc = b1[c];
#pragma unroll 8
        for (int k = 0; k < 64; ++k) acc += Pr[t][k] * w1[k * 32 + c];
        H1[t][c] = fmaxf(acc, 0.0f);
    }
    __syncthreads();
    if (tid < 128) {
        int t = tid >> 4, c = tid & 15;
        float acc = b2[c];
#pragma unroll
        for (int k = 0; k < 32; ++k) acc += H1[t][k] * w2[k * 16 + c];
        H2[t][c] = fmaxf(acc, 0.0f);
    }
    __syncthreads();
    if (tid < 8) {
        int t = tid;
        float acc = b3[0];
#pragma unroll
        for (int k = 0; k < 16; ++k) acc += H2[t][k] * w3[k];
        float occ = softplusf_(acc);
        int l = ltp[p * 8 + t];
        OC[t] = occ / cap[l];
    }
    __syncthreads();
    if (tid == 0) {
        float s = 0.0f;
#pragma unroll
        for (int t = 0; t < 8; ++t) s += OC[t];
        out[p] = s;
    }
}

// ---------------------------------------------------------------------------
extern "C" void kernel_launch(void* const* d_in, const int* in_sizes, int n_in,
                              void* d_out, int out_size, void* d_ws, size_t ws_size,
                              hipStream_t stream) {
    const float* ft   = (const float*)d_in[0];
    const float* fpk  = (const float*)d_in[1];
    const float* fps  = (const float*)d_in[2];
    const float* cap  = (const float*)d_in[3];
    const float* pe_w1 = (const float*)d_in[4];
    const float* pe_b1 = (const float*)d_in[5];
    const float* pe_w2 = (const float*)d_in[6];
    const float* pe_b2 = (const float*)d_in[7];
    const float* le_w1 = (const float*)d_in[8];
    const float* le_b1 = (const float*)d_in[9];
    const float* le_w2 = (const float*)d_in[10];
    const float* le_b2 = (const float*)d_in[11];
    const float* de_w1 = (const float*)d_in[12];
    const float* de_b1 = (const float*)d_in[13];
    const float* de_w2 = (const float*)d_in[14];
    const float* de_b2 = (const float*)d_in[15];
    const float* pgru_wx = (const float*)d_in[16];
    const float* pgru_wh = (const float*)d_in[17];
    const float* pgru_bx = (const float*)d_in[18];
    const float* pgru_bh = (const float*)d_in[19];
    const float* lgru_wx = (const float*)d_in[20];
    const float* lgru_wh = (const float*)d_in[21];
    const float* lgru_bx = (const float*)d_in[22];
    const float* lgru_bh = (const float*)d_in[23];
    const float* dgru_wx = (const float*)d_in[24];
    const float* dgru_wh = (const float*)d_in[25];
    const float* dgru_bx = (const float*)d_in[26];
    const float* dgru_bh = (const float*)d_in[27];
    const float* ro_w1 = (const float*)d_in[28];
    const float* ro_b1 = (const float*)d_in[29];
    const float* ro_w2 = (const float*)d_in[30];
    const float* ro_b2 = (const float*)d_in[31];
    const float* ro_w3 = (const float*)d_in[32];
    const float* ro_b3 = (const float*)d_in[33];
    const int* ltp   = (const int*)d_in[34];
    const int* ntp   = (const int*)d_in[35];
    const int* ptl   = (const int*)d_in[36];
    const int* ptn   = (const int*)d_in[37];
    const int* ltn   = (const int*)d_in[38];
    const int* nodes = (const int*)d_in[39];
    const int* ldt   = (const int*)d_in[40];
    float* out = (float*)d_out;

    char* ws = (char*)d_ws;
    float* path_state = (float*)ws;      ws += (size_t)PN * 64 * 4;
    float* link_state = (float*)ws;      ws += (size_t)LN * 64 * 4;
    float* device_state = (float*)ws;    ws += (size_t)NN * 64 * 4;
    float* pss = (float*)ws;             ws += (size_t)PN * 9 * 64 * 4;
    unsigned short* xproj = (unsigned short*)ws;  ws += (size_t)PN * TT * 192 * 2;

    k_path_encode<<<PN / 4, 256, 0, stream>>>(ft, fpk, fps, pe_w1, pe_b1, pe_w2,
                                              pe_b2, path_state);
    k_link_encode<<<LN / 4, 256, 0, stream>>>(cap, ft, ptl, ldt, le_w1, le_b1,
                                              le_w2, le_b2, link_state);
    k_device_encode<<<NN / 4, 256, 0, stream>>>(link_state, ltn, nodes, de_w1,
                                                de_b1, de_w2, de_b2, device_state);
    for (int it = 0; it < ITER; ++it) {
        k_xproj<<<(PN * TT) / 64, 256, 0, stream>>>(link_state, device_state, ltp,
                                                    ntp, pgru_wx, pgru_bx, xproj);
        k_pscan<<<PN / 32, 256, 0, stream>>>(pgru_wh, pgru_bh, xproj, path_state,
                                             pss);
        k_edge_update<<<LN / 8, 256, 0, stream>>>(lgru_wx, lgru_wh, lgru_bx,
                                                  lgru_bh, ptl, KG, pss, link_state);
        k_edge_update<<<NN / 8, 256, 0, stream>>>(dgru_wx, dgru_wh, dgru_bx,
                                                  dgru_bh, ptn, K2G, pss,
                                                  device_state);
    }
    k_readout<<<PN, 256, 0, stream>>>(pss, ro_w1, ro_b1, ro_w2, ro_b2, ro_w3,
                                      ro_b3, cap, ltp, out);
}

// Round 2
// 682.217 us; speedup vs baseline: 2.1106x; 2.1106x over previous
//
#include <hip/hip_runtime.h>
#include <hip/hip_bf16.h>

// Problem constants
static constexpr int PN = 16384;  // paths
static constexpr int TT = 8;      // seq len
static constexpr int LN = 4096;   // links
static constexpr int KG = 16;     // path_to_link K
static constexpr int NN = 2048;   // nodes
static constexpr int K2G = 32;    // path_to_node K2
static constexpr int MG = 8;      // link_to_node M
static constexpr int ITER = 8;

typedef __attribute__((ext_vector_type(8))) short short8b;   // 8 bf16 (4 VGPRs)
typedef __attribute__((ext_vector_type(4))) float f32x4;

__device__ __forceinline__ float sigmoidf_(float x) {
    return 1.0f / (1.0f + __expf(-x));
}
__device__ __forceinline__ float tanhf_(float x) {
    float e = __expf(2.0f * x);
    return 1.0f - 2.0f / (e + 1.0f);
}
__device__ __forceinline__ float softplusf_(float x) {
    return fmaxf(x, 0.0f) + log1pf(__expf(-fabsf(x)));
}
__device__ __forceinline__ unsigned short f2bf(float f) {
    unsigned int x = __float_as_uint(f);
    unsigned int r = (x + 0x7fffu + ((x >> 16) & 1u)) >> 16;
    return (unsigned short)r;
}

// ---------------------------------------------------------------------------
// K0: weight transpose+cast: src fp32 [64][192] -> dst bf16 [192][64]
// ---------------------------------------------------------------------------
__global__ __launch_bounds__(256) void k_wT(const float* __restrict__ src,
                                            unsigned short* __restrict__ dst) {
    int o = blockIdx.x * 256 + threadIdx.x;   // 0..12287
    int n = o >> 6, k = o & 63;
    dst[o] = f2bf(src[k * 192 + n]);
}

// ---------------------------------------------------------------------------
// K1: path encoder MLP2 (3 -> 64 -> 64)
// ---------------------------------------------------------------------------
__global__ __launch_bounds__(256) void k_path_encode(
    const float* __restrict__ ft, const float* __restrict__ fpk,
    const float* __restrict__ fps,
    const float* __restrict__ w1, const float* __restrict__ b1,
    const float* __restrict__ w2, const float* __restrict__ b2,
    float* __restrict__ path_state)
{
    __shared__ float h1s[4][64];
    int tid = threadIdx.x;
    int rl = tid >> 6, d = tid & 63;
    int row = blockIdx.x * 4 + rl;
    float x0 = ft[row]  * 1e-4f;
    float x1 = fpk[row] * 1e-3f;
    float x2 = fps[row] * 1e-3f;
    float h = b1[d] + x0 * w1[d] + x1 * w1[64 + d] + x2 * w1[128 + d];
    h1s[rl][d] = fmaxf(h, 0.0f);
    __syncthreads();
    float acc = b2[d];
#pragma unroll 8
    for (int k = 0; k < 64; ++k) acc += h1s[rl][k] * w2[k * 64 + d];
    path_state[(size_t)row * 64 + d] = fmaxf(acc, 0.0f);
}

// ---------------------------------------------------------------------------
// K2: link encoder
// ---------------------------------------------------------------------------
__global__ __launch_bounds__(256) void k_link_encode(
    const float* __restrict__ cap, const float* __restrict__ ft,
    const int* __restrict__ ptl, const int* __restrict__ ldt,
    const float* __restrict__ w1, const float* __restrict__ b1,
    const float* __restrict__ w2, const float* __restrict__ b2,
    float* __restrict__ link_state)
{
    __shared__ float h1s[4][64];
    int tid = threadIdx.x;
    int rl = tid >> 6, d = tid & 63;
    int row = blockIdx.x * 4 + rl;
    float v = 0.0f;
    if (d < 16) v = ft[ptl[(row * 16 + d) * 2]];
    v += __shfl_down(v, 8);
    v += __shfl_down(v, 4);
    v += __shfl_down(v, 2);
    v += __shfl_down(v, 1);
    float ssum = __shfl(v, 0);
    float c = cap[row];
    float load = ssum / (c * 1e9f);
    float x0 = c * 0.01f;
    float x1 = load;
    float x2 = (ldt[row] == 0) ? 1.0f : 0.0f;
    float h = b1[d] + x0 * w1[d] + x1 * w1[64 + d] + x2 * w1[128 + d];
    h1s[rl][d] = fmaxf(h, 0.0f);
    __syncthreads();
    float acc = b2[d];
#pragma unroll 8
    for (int k = 0; k < 64; ++k) acc += h1s[rl][k] * w2[k * 64 + d];
    link_state[(size_t)row * 64 + d] = fmaxf(acc, 0.0f);
}

// ---------------------------------------------------------------------------
// K3: device encoder
// ---------------------------------------------------------------------------
__global__ __launch_bounds__(256) void k_device_encode(
    const float* __restrict__ link_state, const int* __restrict__ ltn,
    const int* __restrict__ nodes,
    const float* __restrict__ w1, const float* __restrict__ b1,
    const float* __restrict__ w2, const float* __restrict__ b2,
    float* __restrict__ device_state)
{
    __shared__ float h1s[4][64];
    int tid = threadIdx.x;
    int rl = tid >> 6, d = tid & 63;
    int row = blockIdx.x * 4 + rl;
    float s = 0.0f;
#pragma unroll
    for (int m = 0; m < MG; ++m)
        s += link_state[(size_t)ltn[row * MG + m] * 64 + d];
#pragma unroll
    for (int o = 32; o > 0; o >>= 1) s += __shfl_xor(s, o);
    float dlm = s * (1.0f / 64.0f);
    float enc = (nodes[row] == 0) ? 1.0f : 0.0f;
    float h = b1[d] + enc * w1[d] + dlm * w1[64 + d];
    h1s[rl][d] = fmaxf(h, 0.0f);
    __syncthreads();
    float acc = b2[d];
#pragma unroll 8
    for (int k = 0; k < 64; ++k) acc += h1s[rl][k] * w2[k * 64 + d];
    device_state[(size_t)row * 64 + d] = fmaxf(acc, 0.0f);
}

// ---------------------------------------------------------------------------
// K4: fused x-gather + xproj + 8-step GRU scan, bf16 MFMA 16x16x32.
// 32 paths/block, 4 waves. Wave w owns N-tiles {w, 4+w, 8+w} => gate-aligned
// (z/r/c for a given (row,d) in the same lane). Weights' B-frags in registers.
// pss written fp32 [p][8][64] (t index = step, i.e. reference t+1).
// ---------------------------------------------------------------------------
__global__ __launch_bounds__(256, 3) void k_pscan(
    const float* __restrict__ ls, const float* __restrict__ dst,
    const int* __restrict__ ltp, const int* __restrict__ ntp,
    const unsigned short* __restrict__ wxT,   // bf16 [192][64]
    const unsigned short* __restrict__ whT,   // bf16 [192][64]
    const float* __restrict__ bx, const float* __restrict__ bh,
    float* __restrict__ path_state, float* __restrict__ pss)
{
    __shared__ __align__(16) unsigned short Xs[8][32][72];  // bf16, padded
    __shared__ __align__(16) float Hf[32][68];              // fp32 h (hold)
    __shared__ __align__(16) unsigned short Hb[32][72];     // bf16 h (A-frag)
    int tid = threadIdx.x;
    int p0 = blockIdx.x * 32;

    // stage h0 (fp32 + bf16 copies)
    {
        int r = tid >> 3, c0 = (tid & 7) * 8;
        const float4* src = (const float4*)(path_state + (size_t)(p0 + r) * 64 + c0);
        float4 a = src[0], b = src[1];
        *(float4*)&Hf[r][c0] = a;
        *(float4*)&Hf[r][c0 + 4] = b;
        ushort4 u0, u1;
        u0.x = f2bf(a.x); u0.y = f2bf(a.y); u0.z = f2bf(a.z); u0.w = f2bf(a.w);
        u1.x = f2bf(b.x); u1.y = f2bf(b.y); u1.z = f2bf(b.z); u1.w = f2bf(b.w);
        *(ushort4*)&Hb[r][c0] = u0;
        *(ushort4*)&Hb[r][c0 + 4] = u1;
    }
    // gather x = ls[ltp] + dst[ntp] -> bf16 Xs[t][m][k]
    {
        int m = tid & 31, t = tid >> 5;
        int gi = (p0 + m) * TT + t;
        int il = ltp[gi], in = ntp[gi];
        const float4* l4 = (const float4*)(ls + (size_t)il * 64);
        const float4* n4 = (const float4*)(dst + (size_t)in * 64);
#pragma unroll
        for (int j = 0; j < 16; ++j) {
            float4 a = l4[j], b = n4[j];
            ushort4 u;
            u.x = f2bf(a.x + b.x); u.y = f2bf(a.y + b.y);
            u.z = f2bf(a.z + b.z); u.w = f2bf(a.w + b.w);
            *(ushort4*)&Xs[t][m][j * 4] = u;
        }
    }

    int lane = tid & 63, w = tid >> 6;
    int c = lane & 15, q = lane >> 4;
    int d = 16 * w + c;
    // preload B-fragments (constant across steps AND iterations)
    short8b fx[3][2], fh[3][2];
    int gb0 = 16 * w, gb1 = 64 + 16 * w, gb2 = 128 + 16 * w;
    int nb[3] = {gb0 + c, gb1 + c, gb2 + c};
#pragma unroll
    for (int g = 0; g < 3; ++g)
#pragma unroll
        for (int kt = 0; kt < 2; ++kt) {
            int off = nb[g] * 64 + kt * 32 + q * 8;
            fx[g][kt] = *(const short8b*)(wxT + off);
            fh[g][kt] = *(const short8b*)(whT + off);
        }
    float bz = bx[d] + bh[d];
    float br = bx[64 + d] + bh[64 + d];
    float bxc = bx[128 + d];
    float bhc = bh[128 + d];
    __syncthreads();

    for (int t = 0; t < TT; ++t) {
        f32x4 ax[3][2], ah[3][2];
#pragma unroll
        for (int g = 0; g < 3; ++g)
#pragma unroll
            for (int mt = 0; mt < 2; ++mt) {
                ax[g][mt] = (f32x4){0.f, 0.f, 0.f, 0.f};
                ah[g][mt] = (f32x4){0.f, 0.f, 0.f, 0.f};
            }
#pragma unroll
        for (int mt = 0; mt < 2; ++mt)
#pragma unroll
            for (int kt = 0; kt < 2; ++kt) {
                short8b aX = *(const short8b*)&Xs[t][mt * 16 + c][kt * 32 + q * 8];
                short8b aH = *(const short8b*)&Hb[mt * 16 + c][kt * 32 + q * 8];
#pragma unroll
                for (int g = 0; g < 3; ++g) {
                    ax[g][mt] = __builtin_amdgcn_mfma_f32_16x16x32_bf16(
                        aX, fx[g][kt], ax[g][mt], 0, 0, 0);
                    ah[g][mt] = __builtin_amdgcn_mfma_f32_16x16x32_bf16(
                        aH, fh[g][kt], ah[g][mt], 0, 0, 0);
                }
            }
        float hnv[2][4];
#pragma unroll
        for (int mt = 0; mt < 2; ++mt)
#pragma unroll
            for (int r = 0; r < 4; ++r) {
                int m = mt * 16 + q * 4 + r;
                float z  = sigmoidf_(ax[0][mt][r] + ah[0][mt][r] + bz);
                float rr = sigmoidf_(ax[1][mt][r] + ah[1][mt][r] + br);
                float cc = tanhf_(ax[2][mt][r] + bxc + rr * (ah[2][mt][r] + bhc));
                float hold = Hf[m][d];
                float hn = z * hold + (1.0f - z) * cc;
                hnv[mt][r] = hn;
                pss[((size_t)(p0 + m) * TT + t) * 64 + d] = hn;
            }
        __syncthreads();
#pragma unroll
        for (int mt = 0; mt < 2; ++mt)
#pragma unroll
            for (int r = 0; r < 4; ++r) {
                int m = mt * 16 + q * 4 + r;
                Hf[m][d] = hnv[mt][r];
                Hb[m][d] = f2bf(hnv[mt][r]);
            }
        __syncthreads();
    }
    // final h -> path_state
    {
        int r = tid >> 3, c0 = (tid & 7) * 8;
        float4* dstp = (float4*)(path_state + (size_t)(p0 + r) * 64 + c0);
        dstp[0] = *(const float4*)&Hf[r][c0];
        dstp[1] = *(const float4*)&Hf[r][c0 + 4];
    }
}

// ---------------------------------------------------------------------------
// K6/K7: link/device GRU update via MFMA. 16 rows/block, 4 waves,
// wave w owns gate-aligned N-tiles {w,4+w,8+w}; agg gathered fp32 then bf16.
// ---------------------------------------------------------------------------
__global__ __launch_bounds__(256, 3) void k_edge(
    const unsigned short* __restrict__ wxT, const unsigned short* __restrict__ whT,
    const float* __restrict__ bx, const float* __restrict__ bh,
    const int* __restrict__ p2e, int Kg,
    const float* __restrict__ pss, float* __restrict__ state)
{
    __shared__ __align__(16) unsigned short Ab[16][72];
    __shared__ __align__(16) unsigned short Hb[16][72];
    __shared__ __align__(16) float Hf[16][68];
    int tid = threadIdx.x;
    int r0 = blockIdx.x * 16;
    {
        int r = tid >> 4, c4 = (tid & 15) * 4;
        int row = r0 + r;
        float4 s = {0.f, 0.f, 0.f, 0.f};
        for (int k = 0; k < Kg; ++k) {
            int pi = p2e[((size_t)row * Kg + k) * 2];
            int ti = p2e[((size_t)row * Kg + k) * 2 + 1];
            float4 v = *(const float4*)(pss + ((size_t)pi * TT + (ti - 1)) * 64 + c4);
            s.x += v.x; s.y += v.y; s.z += v.z; s.w += v.w;
        }
        ushort4 ua;
        ua.x = f2bf(s.x); ua.y = f2bf(s.y); ua.z = f2bf(s.z); ua.w = f2bf(s.w);
        *(ushort4*)&Ab[r][c4] = ua;
        float4 hv = *(const float4*)(state + (size_t)row * 64 + c4);
        *(float4*)&Hf[r][c4] = hv;
        ushort4 uh;
        uh.x = f2bf(hv.x); uh.y = f2bf(hv.y); uh.z = f2bf(hv.z); uh.w = f2bf(hv.w);
        *(ushort4*)&Hb[r][c4] = uh;
    }
    __syncthreads();
    int lane = tid & 63, w = tid >> 6;
    int c = lane & 15, q = lane >> 4;
    int d = 16 * w + c;
    int nb[3] = {16 * w + c, 64 + 16 * w + c, 128 + 16 * w + c};
    short8b fx[3][2], fh[3][2];
#pragma unroll
    for (int g = 0; g < 3; ++g)
#pragma unroll
        for (int kt = 0; kt < 2; ++kt) {
            int off = nb[g] * 64 + kt * 32 + q * 8;
            fx[g][kt] = *(const short8b*)(wxT + off);
            fh[g][kt] = *(const short8b*)(whT + off);
        }
    f32x4 ax[3], ah[3];
#pragma unroll
    for (int g = 0; g < 3; ++g) {
        ax[g] = (f32x4){0.f, 0.f, 0.f, 0.f};
        ah[g] = (f32x4){0.f, 0.f, 0.f, 0.f};
    }
#pragma unroll
    for (int kt = 0; kt < 2; ++kt) {
        short8b aA = *(const short8b*)&Ab[c][kt * 32 + q * 8];
        short8b aH = *(const short8b*)&Hb[c][kt * 32 + q * 8];
#pragma unroll
        for (int g = 0; g < 3; ++g) {
            ax[g] = __builtin_amdgcn_mfma_f32_16x16x32_bf16(aA, fx[g][kt], ax[g], 0, 0, 0);
            ah[g] = __builtin_amdgcn_mfma_f32_16x16x32_bf16(aH, fh[g][kt], ah[g], 0, 0, 0);
        }
    }
    float bz = bx[d] + bh[d];
    float br = bx[64 + d] + bh[64 + d];
    float bxc = bx[128 + d];
    float bhc = bh[128 + d];
#pragma unroll
    for (int r = 0; r < 4; ++r) {
        int m = q * 4 + r;
        float z  = sigmoidf_(ax[0][r] + ah[0][r] + bz);
        float rr = sigmoidf_(ax[1][r] + ah[1][r] + br);
        float cc = tanhf_(ax[2][r] + bxc + rr * (ah[2][r] + bhc));
        float hn = z * Hf[m][d] + (1.0f - z) * cc;
        state[(size_t)(r0 + m) * 64 + d] = hn;
    }
}

// ---------------------------------------------------------------------------
// K8: readout MLP (64->32->16->1), softplus, delay sum. One path per block.
// ---------------------------------------------------------------------------
__global__ __launch_bounds__(256) void k_readout(
    const float* __restrict__ pss,
    const float* __restrict__ w1, const float* __restrict__ b1,
    const float* __restrict__ w2, const float* __restrict__ b2,
    const float* __restrict__ w3, const float* __restrict__ b3,
    const float* __restrict__ cap, const int* __restrict__ ltp,
    float* __restrict__ out)
{
    __shared__ __align__(16) float Pr[8][68];
    __shared__ float H1[8][33];
    __shared__ float H2[8][17];
    __shared__ float OC[8];
    int tid = threadIdx.x;
    int p = blockIdx.x;
    if (tid < 128) {
        int r = tid >> 4, q = tid & 15;
        *(float4*)&Pr[r][q * 4] =
            *(const float4*)&pss[((size_t)p * TT + r) * 64 + q * 4];
    }
    __syncthreads();
    {
        int t = tid >> 5, c = tid & 31;
        float acc = b1[c];
#pragma unroll 8
        for (int k = 0; k < 64; ++k) acc += Pr[t][k] * w1[k * 32 + c];
        H1[t][c] = fmaxf(acc, 0.0f);
    }
    __syncthreads();
    if (tid < 128) {
        int t = tid >> 4, c = tid & 15;
        float acc = b2[c];
#pragma unroll
        for (int k = 0; k < 32; ++k) acc += H1[t][k] * w2[k * 16 + c];
        H2[t][c] = fmaxf(acc, 0.0f);
    }
    __syncthreads();
    if (tid < 8) {
        int t = tid;
        float acc = b3[0];
#pragma unroll
        for (int k = 0; k < 16; ++k) acc += H2[t][k] * w3[k];
        float occ = softplusf_(acc);
        int l = ltp[p * TT + t];
        OC[t] = occ / cap[l];
    }
    __syncthreads();
    if (tid == 0) {
        float s = 0.0f;
#pragma unroll
        for (int t = 0; t < 8; ++t) s += OC[t];
        out[p] = s;
    }
}

// ---------------------------------------------------------------------------
extern "C" void kernel_launch(void* const* d_in, const int* in_sizes, int n_in,
                              void* d_out, int out_size, void* d_ws, size_t ws_size,
                              hipStream_t stream) {
    const float* ft   = (const float*)d_in[0];
    const float* fpk  = (const float*)d_in[1];
    const float* fps  = (const float*)d_in[2];
    const float* cap  = (const float*)d_in[3];
    const float* pe_w1 = (const float*)d_in[4];
    const float* pe_b1 = (const float*)d_in[5];
    const float* pe_w2 = (const float*)d_in[6];
    const float* pe_b2 = (const float*)d_in[7];
    const float* le_w1 = (const float*)d_in[8];
    const float* le_b1 = (const float*)d_in[9];
    const float* le_w2 = (const float*)d_in[10];
    const float* le_b2 = (const float*)d_in[11];
    const float* de_w1 = (const float*)d_in[12];
    const float* de_b1 = (const float*)d_in[13];
    const float* de_w2 = (const float*)d_in[14];
    const float* de_b2 = (const float*)d_in[15];
    const float* pgru_wx = (const float*)d_in[16];
    const float* pgru_wh = (const float*)d_in[17];
    const float* pgru_bx = (const float*)d_in[18];
    const float* pgru_bh = (const float*)d_in[19];
    const float* lgru_wx = (const float*)d_in[20];
    const float* lgru_wh = (const float*)d_in[21];
    const float* lgru_bx = (const float*)d_in[22];
    const float* lgru_bh = (const float*)d_in[23];
    const float* dgru_wx = (const float*)d_in[24];
    const float* dgru_wh = (const float*)d_in[25];
    const float* dgru_bx = (const float*)d_in[26];
    const float* dgru_bh = (const float*)d_in[27];
    const float* ro_w1 = (const float*)d_in[28];
    const float* ro_b1 = (const float*)d_in[29];
    const float* ro_w2 = (const float*)d_in[30];
    const float* ro_b2 = (const float*)d_in[31];
    const float* ro_w3 = (const float*)d_in[32];
    const float* ro_b3 = (const float*)d_in[33];
    const int* ltp   = (const int*)d_in[34];
    const int* ntp   = (const int*)d_in[35];
    const int* ptl   = (const int*)d_in[36];
    const int* ptn   = (const int*)d_in[37];
    const int* ltn   = (const int*)d_in[38];
    const int* nodes = (const int*)d_in[39];
    const int* ldt   = (const int*)d_in[40];
    float* out = (float*)d_out;

    char* ws = (char*)d_ws;
    float* path_state = (float*)ws;      ws += (size_t)PN * 64 * 4;
    float* link_state = (float*)ws;      ws += (size_t)LN * 64 * 4;
    float* device_state = (float*)ws;    ws += (size_t)NN * 64 * 4;
    float* pss = (float*)ws;             ws += (size_t)PN * TT * 64 * 4;
    unsigned short* pwxT = (unsigned short*)ws; ws += 192 * 64 * 2;
    unsigned short* pwhT = (unsigned short*)ws; ws += 192 * 64 * 2;
    unsigned short* lwxT = (unsigned short*)ws; ws += 192 * 64 * 2;
    unsigned short* lwhT = (unsigned short*)ws; ws += 192 * 64 * 2;
    unsigned short* dwxT = (unsigned short*)ws; ws += 192 * 64 * 2;
    unsigned short* dwhT = (unsigned short*)ws; ws += 192 * 64 * 2;

    k_wT<<<48, 256, 0, stream>>>(pgru_wx, pwxT);
    k_wT<<<48, 256, 0, stream>>>(pgru_wh, pwhT);
    k_wT<<<48, 256, 0, stream>>>(lgru_wx, lwxT);
    k_wT<<<48, 256, 0, stream>>>(lgru_wh, lwhT);
    k_wT<<<48, 256, 0, stream>>>(dgru_wx, dwxT);
    k_wT<<<48, 256, 0, stream>>>(dgru_wh, dwhT);

    k_path_encode<<<PN / 4, 256, 0, stream>>>(ft, fpk, fps, pe_w1, pe_b1, pe_w2,
                                              pe_b2, path_state);
    k_link_encode<<<LN / 4, 256, 0, stream>>>(cap, ft, ptl, ldt, le_w1, le_b1,
                                              le_w2, le_b2, link_state);
    k_device_encode<<<NN / 4, 256, 0, stream>>>(link_state, ltn, nodes, de_w1,
                                                de_b1, de_w2, de_b2, device_state);
    for (int it = 0; it < ITER; ++it) {
        k_pscan<<<PN / 32, 256, 0, stream>>>(link_state, device_state, ltp, ntp,
                                             pwxT, pwhT, pgru_bx, pgru_bh,
                                             path_state, pss);
        k_edge<<<LN / 16, 256, 0, stream>>>(lwxT, lwhT, lgru_bx, lgru_bh, ptl,
                                            KG, pss, link_state);
        k_edge<<<NN / 16, 256, 0, stream>>>(dwxT, dwhT, dgru_bx, dgru_bh, ptn,
                                            K2G, pss, device_state);
    }
    k_readout<<<PN, 256, 0, stream>>>(pss, ro_w1, ro_b1, ro_w2, ro_b2, ro_w3,
                                      ro_b3, cap, ltp, out);
}

// Round 3
// 488.826 us; speedup vs baseline: 2.9456x; 1.3956x over previous
//
#include <hip/hip_runtime.h>
#include <hip/hip_bf16.h>

// Problem constants
static constexpr int PN = 16384;  // paths
static constexpr int TT = 8;      // seq len
static constexpr int LN = 4096;   // links
static constexpr int KG = 16;     // path_to_link K
static constexpr int NN = 2048;   // nodes
static constexpr int K2G = 32;    // path_to_node K2
static constexpr int MG = 8;      // link_to_node M
static constexpr int ITER = 8;

typedef __attribute__((ext_vector_type(8))) short short8b;   // 8 bf16 (4 VGPRs)
typedef __attribute__((ext_vector_type(4))) float f32x4;

__device__ __forceinline__ float sigmoidf_(float x) {
    return 1.0f / (1.0f + __expf(-x));
}
__device__ __forceinline__ float tanhf_(float x) {
    float e = __expf(2.0f * x);
    return 1.0f - 2.0f / (e + 1.0f);
}
__device__ __forceinline__ float softplusf_(float x) {
    return fmaxf(x, 0.0f) + log1pf(__expf(-fabsf(x)));
}
__device__ __forceinline__ unsigned short f2bf(float f) {
    unsigned int x = __float_as_uint(f);
    unsigned int r = (x + 0x7fffu + ((x >> 16) & 1u)) >> 16;
    return (unsigned short)r;
}
__device__ __forceinline__ float bf2f(unsigned short u) {
    return __uint_as_float(((unsigned int)u) << 16);
}

// ---------------------------------------------------------------------------
// K0: 6 weight transposes+casts in one launch: fp32 [64][192] -> bf16 [192][64]
// ---------------------------------------------------------------------------
__global__ __launch_bounds__(256) void k_wT6(
    const float* __restrict__ s0, const float* __restrict__ s1,
    const float* __restrict__ s2, const float* __restrict__ s3,
    const float* __restrict__ s4, const float* __restrict__ s5,
    unsigned short* __restrict__ d0, unsigned short* __restrict__ d1,
    unsigned short* __restrict__ d2, unsigned short* __restrict__ d3,
    unsigned short* __restrict__ d4, unsigned short* __restrict__ d5)
{
    int b = blockIdx.x;
    int mi = b / 48;
    int o = (b % 48) * 256 + threadIdx.x;  // 0..12287
    const float* src = (mi == 0) ? s0 : (mi == 1) ? s1 : (mi == 2) ? s2
                     : (mi == 3) ? s3 : (mi == 4) ? s4 : s5;
    unsigned short* dst = (mi == 0) ? d0 : (mi == 1) ? d1 : (mi == 2) ? d2
                        : (mi == 3) ? d3 : (mi == 4) ? d4 : d5;
    int n = o >> 6, k = o & 63;
    dst[o] = f2bf(src[k * 192 + n]);
}

// ---------------------------------------------------------------------------
// K1: path encoder MLP2 (3 -> 64 -> 64)
// ---------------------------------------------------------------------------
__global__ __launch_bounds__(256) void k_path_encode(
    const float* __restrict__ ft, const float* __restrict__ fpk,
    const float* __restrict__ fps,
    const float* __restrict__ w1, const float* __restrict__ b1,
    const float* __restrict__ w2, const float* __restrict__ b2,
    float* __restrict__ path_state)
{
    __shared__ float h1s[4][64];
    int tid = threadIdx.x;
    int rl = tid >> 6, d = tid & 63;
    int row = blockIdx.x * 4 + rl;
    float x0 = ft[row]  * 1e-4f;
    float x1 = fpk[row] * 1e-3f;
    float x2 = fps[row] * 1e-3f;
    float h = b1[d] + x0 * w1[d] + x1 * w1[64 + d] + x2 * w1[128 + d];
    h1s[rl][d] = fmaxf(h, 0.0f);
    __syncthreads();
    float acc = b2[d];
#pragma unroll 8
    for (int k = 0; k < 64; ++k) acc += h1s[rl][k] * w2[k * 64 + d];
    path_state[(size_t)row * 64 + d] = fmaxf(acc, 0.0f);
}

// ---------------------------------------------------------------------------
// K2: link encoder
// ---------------------------------------------------------------------------
__global__ __launch_bounds__(256) void k_link_encode(
    const float* __restrict__ cap, const float* __restrict__ ft,
    const int* __restrict__ ptl, const int* __restrict__ ldt,
    const float* __restrict__ w1, const float* __restrict__ b1,
    const float* __restrict__ w2, const float* __restrict__ b2,
    float* __restrict__ link_state)
{
    __shared__ float h1s[4][64];
    int tid = threadIdx.x;
    int rl = tid >> 6, d = tid & 63;
    int row = blockIdx.x * 4 + rl;
    float v = 0.0f;
    if (d < 16) v = ft[ptl[(row * 16 + d) * 2]];
    v += __shfl_down(v, 8);
    v += __shfl_down(v, 4);
    v += __shfl_down(v, 2);
    v += __shfl_down(v, 1);
    float ssum = __shfl(v, 0);
    float c = cap[row];
    float load = ssum / (c * 1e9f);
    float x0 = c * 0.01f;
    float x1 = load;
    float x2 = (ldt[row] == 0) ? 1.0f : 0.0f;
    float h = b1[d] + x0 * w1[d] + x1 * w1[64 + d] + x2 * w1[128 + d];
    h1s[rl][d] = fmaxf(h, 0.0f);
    __syncthreads();
    float acc = b2[d];
#pragma unroll 8
    for (int k = 0; k < 64; ++k) acc += h1s[rl][k] * w2[k * 64 + d];
    link_state[(size_t)row * 64 + d] = fmaxf(acc, 0.0f);
}

// ---------------------------------------------------------------------------
// K3: device encoder
// ---------------------------------------------------------------------------
__global__ __launch_bounds__(256) void k_device_encode(
    const float* __restrict__ link_state, const int* __restrict__ ltn,
    const int* __restrict__ nodes,
    const float* __restrict__ w1, const float* __restrict__ b1,
    const float* __restrict__ w2, const float* __restrict__ b2,
    float* __restrict__ device_state)
{
    __shared__ float h1s[4][64];
    int tid = threadIdx.x;
    int rl = tid >> 6, d = tid & 63;
    int row = blockIdx.x * 4 + rl;
    float s = 0.0f;
#pragma unroll
    for (int m = 0; m < MG; ++m)
        s += link_state[(size_t)ltn[row * MG + m] * 64 + d];
#pragma unroll
    for (int o = 32; o > 0; o >>= 1) s += __shfl_xor(s, o);
    float dlm = s * (1.0f / 64.0f);
    float enc = (nodes[row] == 0) ? 1.0f : 0.0f;
    float h = b1[d] + enc * w1[d] + dlm * w1[64 + d];
    h1s[rl][d] = fmaxf(h, 0.0f);
    __syncthreads();
    float acc = b2[d];
#pragma unroll 8
    for (int k = 0; k < 64; ++k) acc += h1s[rl][k] * w2[k * 64 + d];
    device_state[(size_t)row * 64 + d] = fmaxf(acc, 0.0f);
}

// ---------------------------------------------------------------------------
// K4: fused x-gather + xproj + 8-step GRU scan, bf16 MFMA 16x16x32.
// 16 paths/block (grid 1024 = 4 blocks/CU), hold-state in registers,
// double-buffered bf16 H in LDS => ONE barrier per step. pss stored bf16.
// ---------------------------------------------------------------------------
__global__ __launch_bounds__(256, 3) void k_pscan(
    const float* __restrict__ ls, const float* __restrict__ dst,
    const int* __restrict__ ltp, const int* __restrict__ ntp,
    const unsigned short* __restrict__ wxT,   // bf16 [192][64]
    const unsigned short* __restrict__ whT,   // bf16 [192][64]
    const float* __restrict__ bx, const float* __restrict__ bh,
    float* __restrict__ path_state, unsigned short* __restrict__ pssb)
{
    __shared__ __align__(16) unsigned short Xs[8][16][72];  // bf16 x, padded
    __shared__ __align__(16) unsigned short Hb[2][16][72];  // bf16 h dbuf
    int tid = threadIdx.x;
    int p0 = blockIdx.x * 16;

    // stage h0 bf16
    {
        int r = tid >> 4, c0 = (tid & 15) * 4;
        float4 a = *(const float4*)(path_state + (size_t)(p0 + r) * 64 + c0);
        ushort4 u;
        u.x = f2bf(a.x); u.y = f2bf(a.y); u.z = f2bf(a.z); u.w = f2bf(a.w);
        *(ushort4*)&Hb[0][r][c0] = u;
    }
    // gather x = ls[ltp] + dst[ntp] -> bf16 Xs[t][m][k]; 2 threads per (m,t)
    {
        int t = tid >> 5, m = (tid >> 1) & 15, half = tid & 1;
        int gi = (p0 + m) * TT + t;
        int il = ltp[gi], in = ntp[gi];
        const float4* l4 = (const float4*)(ls + (size_t)il * 64 + half * 32);
        const float4* n4 = (const float4*)(dst + (size_t)in * 64 + half * 32);
#pragma unroll
        for (int j = 0; j < 8; ++j) {
            float4 a = l4[j], b = n4[j];
            ushort4 u;
            u.x = f2bf(a.x + b.x); u.y = f2bf(a.y + b.y);
            u.z = f2bf(a.z + b.z); u.w = f2bf(a.w + b.w);
            *(ushort4*)&Xs[t][m][half * 32 + j * 4] = u;
        }
    }

    int lane = tid & 63, w = tid >> 6;
    int c = lane & 15, q = lane >> 4;
    int d = 16 * w + c;
    // B-fragments in registers (constant across steps and iterations)
    short8b fx[3][2], fh[3][2];
    int nb[3] = {16 * w + c, 64 + 16 * w + c, 128 + 16 * w + c};
#pragma unroll
    for (int g = 0; g < 3; ++g)
#pragma unroll
        for (int kt = 0; kt < 2; ++kt) {
            int off = nb[g] * 64 + kt * 32 + q * 8;
            fx[g][kt] = *(const short8b*)(wxT + off);
            fh[g][kt] = *(const short8b*)(whT + off);
        }
    float bz = bx[d] + bh[d];
    float br = bx[64 + d] + bh[64 + d];
    float bxc = bx[128 + d];
    float bhc = bh[128 + d];
    // hold-state (fp32) in registers: lane owns rows q*4+r_, col d
    float hold[4];
#pragma unroll
    for (int r_ = 0; r_ < 4; ++r_)
        hold[r_] = path_state[(size_t)(p0 + q * 4 + r_) * 64 + d];
    __syncthreads();

    for (int t = 0; t < TT; ++t) {
        int rb = t & 1, wb = rb ^ 1;
        f32x4 ax[3], ah[3];
#pragma unroll
        for (int g = 0; g < 3; ++g) {
            ax[g] = (f32x4){0.f, 0.f, 0.f, 0.f};
            ah[g] = (f32x4){0.f, 0.f, 0.f, 0.f};
        }
#pragma unroll
        for (int kt = 0; kt < 2; ++kt) {
            short8b aX = *(const short8b*)&Xs[t][c][kt * 32 + q * 8];
            short8b aH = *(const short8b*)&Hb[rb][c][kt * 32 + q * 8];
#pragma unroll
            for (int g = 0; g < 3; ++g) {
                ax[g] = __builtin_amdgcn_mfma_f32_16x16x32_bf16(aX, fx[g][kt], ax[g], 0, 0, 0);
                ah[g] = __builtin_amdgcn_mfma_f32_16x16x32_bf16(aH, fh[g][kt], ah[g], 0, 0, 0);
            }
        }
#pragma unroll
        for (int r_ = 0; r_ < 4; ++r_) {
            float z  = sigmoidf_(ax[0][r_] + ah[0][r_] + bz);
            float rr = sigmoidf_(ax[1][r_] + ah[1][r_] + br);
            float cc = tanhf_(ax[2][r_] + bxc + rr * (ah[2][r_] + bhc));
            float hn = z * hold[r_] + (1.0f - z) * cc;
            hold[r_] = hn;
            Hb[wb][q * 4 + r_][d] = f2bf(hn);
        }
        __syncthreads();
        // cooperative bf16 pss store from the buffer just written
        {
            int r = tid >> 4, c0 = (tid & 15) * 4;
            ushort4 v = *(const ushort4*)&Hb[wb][r][c0];
            *(ushort4*)(pssb + ((size_t)(p0 + r) * TT + t) * 64 + c0) = v;
        }
    }
    // final h (fp32, from registers) -> path_state
#pragma unroll
    for (int r_ = 0; r_ < 4; ++r_)
        path_state[(size_t)(p0 + q * 4 + r_) * 64 + d] = hold[r_];
}

// ---------------------------------------------------------------------------
// K6: merged link+device GRU update. Template Kg => fully unrolled gathers.
// 16 rows/block; indices staged in LDS; pss read as bf16.
// ---------------------------------------------------------------------------
template <int Kg>
__device__ __forceinline__ void edge_body(
    const unsigned short* __restrict__ wxT, const unsigned short* __restrict__ whT,
    const float* __restrict__ bx, const float* __restrict__ bh,
    const int* __restrict__ p2e, const unsigned short* __restrict__ pssb,
    float* __restrict__ state, int blk)
{
    __shared__ int idxs[16 * Kg * 2];
    __shared__ __align__(16) unsigned short Ab[16][72];
    __shared__ __align__(16) unsigned short Hbs[16][72];
    __shared__ __align__(16) float Hf[16][68];
    int tid = threadIdx.x;
    int r0 = blk * 16;
    for (int i = tid; i < 16 * Kg * 2; i += 256)
        idxs[i] = p2e[(size_t)r0 * Kg * 2 + i];
    __syncthreads();
    {
        int r = tid >> 4, c4 = (tid & 15) * 4;
        int row = r0 + r;
        float4 s = {0.f, 0.f, 0.f, 0.f};
#pragma unroll
        for (int k = 0; k < Kg; ++k) {
            int pi = idxs[(r * Kg + k) * 2];
            int ti = idxs[(r * Kg + k) * 2 + 1];
            ushort4 v = *(const ushort4*)(pssb + ((size_t)pi * TT + ti - 1) * 64 + c4);
            s.x += bf2f(v.x); s.y += bf2f(v.y);
            s.z += bf2f(v.z); s.w += bf2f(v.w);
        }
        ushort4 ua;
        ua.x = f2bf(s.x); ua.y = f2bf(s.y); ua.z = f2bf(s.z); ua.w = f2bf(s.w);
        *(ushort4*)&Ab[r][c4] = ua;
        float4 hv = *(const float4*)(state + (size_t)row * 64 + c4);
        *(float4*)&Hf[r][c4] = hv;
        ushort4 uh;
        uh.x = f2bf(hv.x); uh.y = f2bf(hv.y); uh.z = f2bf(hv.z); uh.w = f2bf(hv.w);
        *(ushort4*)&Hbs[r][c4] = uh;
    }
    __syncthreads();
    int lane = tid & 63, w = tid >> 6;
    int c = lane & 15, q = lane >> 4;
    int d = 16 * w + c;
    int nb[3] = {16 * w + c, 64 + 16 * w + c, 128 + 16 * w + c};
    short8b fx[3][2], fh[3][2];
#pragma unroll
    for (int g = 0; g < 3; ++g)
#pragma unroll
        for (int kt = 0; kt < 2; ++kt) {
            int off = nb[g] * 64 + kt * 32 + q * 8;
            fx[g][kt] = *(const short8b*)(wxT + off);
            fh[g][kt] = *(const short8b*)(whT + off);
        }
    f32x4 ax[3], ah[3];
#pragma unroll
    for (int g = 0; g < 3; ++g) {
        ax[g] = (f32x4){0.f, 0.f, 0.f, 0.f};
        ah[g] = (f32x4){0.f, 0.f, 0.f, 0.f};
    }
#pragma unroll
    for (int kt = 0; kt < 2; ++kt) {
        short8b aA = *(const short8b*)&Ab[c][kt * 32 + q * 8];
        short8b aH = *(const short8b*)&Hbs[c][kt * 32 + q * 8];
#pragma unroll
        for (int g = 0; g < 3; ++g) {
            ax[g] = __builtin_amdgcn_mfma_f32_16x16x32_bf16(aA, fx[g][kt], ax[g], 0, 0, 0);
            ah[g] = __builtin_amdgcn_mfma_f32_16x16x32_bf16(aH, fh[g][kt], ah[g], 0, 0, 0);
        }
    }
    float bz = bx[d] + bh[d];
    float br = bx[64 + d] + bh[64 + d];
    float bxc = bx[128 + d];
    float bhc = bh[128 + d];
#pragma unroll
    for (int r = 0; r < 4; ++r) {
        int m = q * 4 + r;
        float z  = sigmoidf_(ax[0][r] + ah[0][r] + bz);
        float rr = sigmoidf_(ax[1][r] + ah[1][r] + br);
        float cc = tanhf_(ax[2][r] + bxc + rr * (ah[2][r] + bhc));
        float hn = z * Hf[m][d] + (1.0f - z) * cc;
        state[(size_t)(r0 + m) * 64 + d] = hn;
    }
}

__global__ __launch_bounds__(256) void k_edge_merged(
    const unsigned short* __restrict__ lwxT, const unsigned short* __restrict__ lwhT,
    const float* __restrict__ lbx, const float* __restrict__ lbh,
    const int* __restrict__ ptl,
    const unsigned short* __restrict__ dwxT, const unsigned short* __restrict__ dwhT,
    const float* __restrict__ dbx, const float* __restrict__ dbh,
    const int* __restrict__ ptn,
    const unsigned short* __restrict__ pssb,
    float* __restrict__ link_state, float* __restrict__ device_state)
{
    int b = blockIdx.x;
    if (b < LN / 16) {
        edge_body<KG>(lwxT, lwhT, lbx, lbh, ptl, pssb, link_state, b);
    } else {
        edge_body<K2G>(dwxT, dwhT, dbx, dbh, ptn, pssb, device_state, b - LN / 16);
    }
}

// ---------------------------------------------------------------------------
// K8: readout MLP (64->32->16->1) + softplus + delay sum. 32 paths/block,
// weights in LDS, 4 chunks of 64 rows.
// ---------------------------------------------------------------------------
__global__ __launch_bounds__(256) void k_readout(
    const unsigned short* __restrict__ pssb,
    const float* __restrict__ w1, const float* __restrict__ b1,
    const float* __restrict__ w2, const float* __restrict__ b2,
    const float* __restrict__ w3, const float* __restrict__ b3,
    const float* __restrict__ cap, const int* __restrict__ ltp,
    float* __restrict__ out)
{
    __shared__ __align__(16) float w1s[64 * 32];
    __shared__ __align__(16) float w2s[32 * 16];
    __shared__ float w3s[16], b1s[32], b2s[16];
    __shared__ __align__(16) float Rf[64][68];
    __shared__ float H1[64][34];
    __shared__ float H2[64][18];
    __shared__ float OCs[256];
    int tid = threadIdx.x;
    size_t g0 = (size_t)blockIdx.x * 256;

    for (int i = tid; i < 2048; i += 256) w1s[i] = w1[i];
    for (int i = tid; i < 512; i += 256) w2s[i] = w2[i];
    if (tid < 16) w3s[tid] = w3[tid];
    if (tid < 32) b1s[tid] = b1[tid];
    if (tid < 16) b2s[tid] = b2[tid];
    float b3v = b3[0];

    for (int ch = 0; ch < 4; ++ch) {
        __syncthreads();
        // stage 64 rows of pssb -> fp32 Rf
#pragma unroll
        for (int u = 0; u < 2; ++u) {
            int li = tid + u * 256;
            int r = li >> 3, c0 = (li & 7) * 8;
            short8b v = *(const short8b*)(pssb + (g0 + ch * 64 + r) * 64 + c0);
            float4 f0, f1;
            f0.x = bf2f((unsigned short)v[0]); f0.y = bf2f((unsigned short)v[1]);
            f0.z = bf2f((unsigned short)v[2]); f0.w = bf2f((unsigned short)v[3]);
            f1.x = bf2f((unsigned short)v[4]); f1.y = bf2f((unsigned short)v[5]);
            f1.z = bf2f((unsigned short)v[6]); f1.w = bf2f((unsigned short)v[7]);
            *(float4*)&Rf[r][c0] = f0;
            *(float4*)&Rf[r][c0 + 4] = f1;
        }
        __syncthreads();
        // layer1: 64 -> 32, thread = (row, 8 cols)
        {
            int r = tid >> 2, jg = tid & 3;
            float acc[8];
#pragma unroll
            for (int j = 0; j < 8; ++j) acc[j] = 0.f;
#pragma unroll 8
            for (int k = 0; k < 64; ++k) {
                float x = Rf[r][k];
                float4 wa = *(const float4*)&w1s[k * 32 + jg * 8];
                float4 wb = *(const float4*)&w1s[k * 32 + jg * 8 + 4];
                acc[0] += x * wa.x; acc[1] += x * wa.y;
                acc[2] += x * wa.z; acc[3] += x * wa.w;
                acc[4] += x * wb.x; acc[5] += x * wb.y;
                acc[6] += x * wb.z; acc[7] += x * wb.w;
            }
#pragma unroll
            for (int j = 0; j < 8; ++j)
                H1[r][jg * 8 + j] = fmaxf(acc[j] + b1s[jg * 8 + j], 0.0f);
        }
        __syncthreads();
        // layer2: 32 -> 16, thread = (row, 4 cols)
        {
            int r = tid >> 2, jg = tid & 3;
            float acc[4];
#pragma unroll
            for (int j = 0; j < 4; ++j) acc[j] = 0.f;
#pragma unroll 8
            for (int k = 0; k < 32; ++k) {
                float x = H1[r][k];
                float4 wv = *(const float4*)&w2s[k * 16 + jg * 4];
                acc[0] += x * wv.x; acc[1] += x * wv.y;
                acc[2] += x * wv.z; acc[3] += x * wv.w;
            }
#pragma unroll
            for (int j = 0; j < 4; ++j)
                H2[r][jg * 4 + j] = fmaxf(acc[j] + b2s[jg * 4 + j], 0.0f);
        }
        __syncthreads();
        // layer3: 16 -> 1, softplus, /cap
        if (tid < 64) {
            int r = tid;
            float acc = b3v;
#pragma unroll
            for (int k = 0; k < 16; ++k) acc += H2[r][k] * w3s[k];
            float occ = softplusf_(acc);
            size_t pr = g0 + ch * 64 + r;
            OCs[ch * 64 + r] = occ / cap[ltp[pr]];
        }
    }
    __syncthreads();
    if (tid < 32) {
        float s = 0.0f;
#pragma unroll
        for (int j = 0; j < 8; ++j) s += OCs[tid * 8 + j];
        out[blockIdx.x * 32 + tid] = s;
    }
}

// ---------------------------------------------------------------------------
extern "C" void kernel_launch(void* const* d_in, const int* in_sizes, int n_in,
                              void* d_out, int out_size, void* d_ws, size_t ws_size,
                              hipStream_t stream) {
    const float* ft   = (const float*)d_in[0];
    const float* fpk  = (const float*)d_in[1];
    const float* fps  = (const float*)d_in[2];
    const float* cap  = (const float*)d_in[3];
    const float* pe_w1 = (const float*)d_in[4];
    const float* pe_b1 = (const float*)d_in[5];
    const float* pe_w2 = (const float*)d_in[6];
    const float* pe_b2 = (const float*)d_in[7];
    const float* le_w1 = (const float*)d_in[8];
    const float* le_b1 = (const float*)d_in[9];
    const float* le_w2 = (const float*)d_in[10];
    const float* le_b2 = (const float*)d_in[11];
    const float* de_w1 = (const float*)d_in[12];
    const float* de_b1 = (const float*)d_in[13];
    const float* de_w2 = (const float*)d_in[14];
    const float* de_b2 = (const float*)d_in[15];
    const float* pgru_wx = (const float*)d_in[16];
    const float* pgru_wh = (const float*)d_in[17];
    const float* pgru_bx = (const float*)d_in[18];
    const float* pgru_bh = (const float*)d_in[19];
    const float* lgru_wx = (const float*)d_in[20];
    const float* lgru_wh = (const float*)d_in[21];
    const float* lgru_bx = (const float*)d_in[22];
    const float* lgru_bh = (const float*)d_in[23];
    const float* dgru_wx = (const float*)d_in[24];
    const float* dgru_wh = (const float*)d_in[25];
    const float* dgru_bx = (const float*)d_in[26];
    const float* dgru_bh = (const float*)d_in[27];
    const float* ro_w1 = (const float*)d_in[28];
    const float* ro_b1 = (const float*)d_in[29];
    const float* ro_w2 = (const float*)d_in[30];
    const float* ro_b2 = (const float*)d_in[31];
    const float* ro_w3 = (const float*)d_in[32];
    const float* ro_b3 = (const float*)d_in[33];
    const int* ltp   = (const int*)d_in[34];
    const int* ntp   = (const int*)d_in[35];
    const int* ptl   = (const int*)d_in[36];
    const int* ptn   = (const int*)d_in[37];
    const int* ltn   = (const int*)d_in[38];
    const int* nodes = (const int*)d_in[39];
    const int* ldt   = (const int*)d_in[40];
    float* out = (float*)d_out;

    char* ws = (char*)d_ws;
    float* path_state = (float*)ws;      ws += (size_t)PN * 64 * 4;
    float* link_state = (float*)ws;      ws += (size_t)LN * 64 * 4;
    float* device_state = (float*)ws;    ws += (size_t)NN * 64 * 4;
    unsigned short* pssb = (unsigned short*)ws; ws += (size_t)PN * TT * 64 * 2;
    unsigned short* pwxT = (unsigned short*)ws; ws += 192 * 64 * 2;
    unsigned short* pwhT = (unsigned short*)ws; ws += 192 * 64 * 2;
    unsigned short* lwxT = (unsigned short*)ws; ws += 192 * 64 * 2;
    unsigned short* lwhT = (unsigned short*)ws; ws += 192 * 64 * 2;
    unsigned short* dwxT = (unsigned short*)ws; ws += 192 * 64 * 2;
    unsigned short* dwhT = (unsigned short*)ws; ws += 192 * 64 * 2;

    k_wT6<<<288, 256, 0, stream>>>(pgru_wx, pgru_wh, lgru_wx, lgru_wh, dgru_wx,
                                   dgru_wh, pwxT, pwhT, lwxT, lwhT, dwxT, dwhT);

    k_path_encode<<<PN / 4, 256, 0, stream>>>(ft, fpk, fps, pe_w1, pe_b1, pe_w2,
                                              pe_b2, path_state);
    k_link_encode<<<LN / 4, 256, 0, stream>>>(cap, ft, ptl, ldt, le_w1, le_b1,
                                              le_w2, le_b2, link_state);
    k_device_encode<<<NN / 4, 256, 0, stream>>>(link_state, ltn, nodes, de_w1,
                                                de_b1, de_w2, de_b2, device_state);
    for (int it = 0; it < ITER; ++it) {
        k_pscan<<<PN / 16, 256, 0, stream>>>(link_state, device_state, ltp, ntp,
                                             pwxT, pwhT, pgru_bx, pgru_bh,
                                             path_state, pssb);
        k_edge_merged<<<LN / 16 + NN / 16, 256, 0, stream>>>(
            lwxT, lwhT, lgru_bx, lgru_bh, ptl,
            dwxT, dwhT, dgru_bx, dgru_bh, ptn,
            pssb, link_state, device_state);
    }
    k_readout<<<PN / 32, 256, 0, stream>>>(pssb, ro_w1, ro_b1, ro_w2, ro_b2,
                                           ro_w3, ro_b3, cap, ltp, out);
}